// Round 1
// baseline (60.450 us; speedup 1.0000x reference)
//
#include <hip/hip_runtime.h>

// BS=16, SQ=128, NQ=21, NK=7, D=256
// Output 0: attn_out (16,128,21,7,256) = keys broadcast over q  (softmax over
//           size-1 axis == 1.0 identically, so weights*keys == keys)
// Output 1: attn_weights (16,128,21,7,1) == 1.0
//
// d_out layout: [attn_out 77,070,336 fp32][attn_weights 301,056 fp32]

#define NBS      2048   // BS*SQ
#define NKD4     448    // NK*D/4 = 7*256/4 float4s per (b,s) key row
#define NQ_      21
#define W4       75264  // 301056/4 float4s of ones
#define ONES_BLK 168    // W4 / 448

__global__ __launch_bounds__(448) void bahdanau_bcast_kernel(
    const float4* __restrict__ keys, float4* __restrict__ out) {
    const int b = blockIdx.x;
    const int t = threadIdx.x;
    if (b < NBS) {
        // copy this (b,s)'s 7x256 key row, replicated 21 times over q
        const float4 v = keys[(size_t)b * NKD4 + t];
        float4* dst = out + (size_t)b * (NQ_ * NKD4) + t;
        #pragma unroll
        for (int q = 0; q < NQ_; ++q) {
            dst[(size_t)q * NKD4] = v;
        }
    } else {
        // attn_weights = 1.0f
        const size_t base = (size_t)NBS * NQ_ * NKD4;  // 19,267,584 float4
        const int idx = (b - NBS) * NKD4 + t;
        out[base + idx] = make_float4(1.0f, 1.0f, 1.0f, 1.0f);
    }
}

extern "C" void kernel_launch(void* const* d_in, const int* in_sizes, int n_in,
                              void* d_out, int out_size, void* d_ws, size_t ws_size,
                              hipStream_t stream) {
    const float4* keys = (const float4*)d_in[1];  // (16,128,1,7,256) fp32
    float4* out = (float4*)d_out;
    hipLaunchKernelGGL(bahdanau_bcast_kernel,
                       dim3(NBS + ONES_BLK), dim3(NKD4), 0, stream,
                       keys, out);
}